// Round 1
// baseline (14001.425 us; speedup 1.0000x reference)
//
#include <hip/hip_runtime.h>
#include <cstdint>
#include <cstddef>

// MirrorLM forward, fp32 end-to-end.
//  B=32 T=2048 V=50257 D=H=512 NH=2 HD=256
// R4: scan sync rebuilt around a write-once NaN-sentinel h history:
//  - hist[t][B][H] lives in the dead x1 buffer (exactly 128 MiB)
//  - producers fire-and-forget sc0sc1 stores (no store-ack wait, no flags)
//  - consumers poll the data itself; validity detected via NaN propagation
//    through the MAC (am[0][b] is NaN iff any h input is still sentinel)
//  - fast_W==0 slices skip their MAC (input-agnostic: zero slice => zero contrib)
// GEMM phase unchanged from R2 (passed, absmax 0.0039).

#define B_ 32
#define T_ 2048
#define V_ 50257
#define D_ 512
#define H_ 512
#define NH_ 2
#define BT_ (B_*T_)   // 65536

typedef float f32x4 __attribute__((ext_vector_type(4)));

// ---- workspace layout (bytes). Requires ~404 MB of d_ws. ----
#define OFF_X0    ((size_t)0)                          // [BT][512] f32, later reused as xin
#define OFF_X1    (OFF_X0 + (size_t)BT_*D_*4)          // [BT][512] f32 (gated x), reused as h history
#define OFF_XZ    (OFF_X1 + (size_t)BT_*D_*4)          // [BT][512] f32 (xz)
#define OFF_SMALL (OFF_XZ + (size_t)BT_*D_*4)
#define OFF_RBUF  (OFF_SMALL)                          // [BT][NH][2] f32 num/den = 1 MB
#define OFF_KSUM  (OFF_RBUF + (size_t)BT_*NH_*2*4)     // [B][512]
#define OFF_KVSUM (OFF_KSUM + (size_t)B_*D_*4)         // [B][512]
#define OFF_FLAGS (OFF_KVSUM + (size_t)B_*D_*4)        // (unused in R4, kept in zero span)
#define OFF_HBUF  (OFF_FLAGS + 16384)                  // (unused in R4)
#define OFF_HLN   (OFF_HBUF + (size_t)2*B_*H_*4)       // LN'd h: [32][512]
#define ZERO_F4   ((OFF_HBUF - OFF_SMALL) / 16)        // zero RBUF..FLAGS

__device__ __forceinline__ float phi_f(float x) {           // elu(x)+1
  return x > 0.f ? x + 1.f : expf(x);
}
__device__ __forceinline__ float sigm_f(float x) {
  return 1.f / (1.f + expf(-x));
}

// ---------------- zero small state ----------------
__global__ __launch_bounds__(256) void zero_k(float4* __restrict__ p, int n) {
  int i = blockIdx.x * 256 + threadIdx.x;
  if (i < n) p[i] = make_float4(0.f, 0.f, 0.f, 0.f);
}

// ---------------- NaN-fill the h history (sentinel) ----------------
__global__ __launch_bounds__(256) void fillnan_k(uint4* __restrict__ p) {
  size_t i = (size_t)blockIdx.x * 256 + threadIdx.x;
  uint4 v;
  v.x = 0x7FC00000u; v.y = 0x7FC00000u; v.z = 0x7FC00000u; v.w = 0x7FC00000u;
  p[i] = v;
}

// ---------------- embedding gather ----------------
__global__ __launch_bounds__(256) void embed_k(const int* __restrict__ ids,
                                               const float* __restrict__ emb,
                                               float* __restrict__ x0) {
  size_t idx = (size_t)blockIdx.x * 256 + threadIdx.x;   // over BT*128 float4
  int row = (int)(idx >> 7), c = (int)(idx & 127);
  int id = ids[row];
  ((float4*)x0)[idx] = ((const float4*)emb)[(size_t)id * 128 + c];
}

// ---------------- tiled fp32 GEMM, Y = X @ W^T, 64x64x32 tiles ----------------
// MODE 0: KV   -> phi(X@Wk^T), X@Wv^T; atomicAdd k_sum/kv_sum (reduce over t)
// MODE 1: Q    -> phi(X@Wq^T); atomicAdd num/den partials vs kv_sum/k_sum
// MODE 2: GATE -> gate=sigmoid(X@Wg^T+bg); x1 = gate*r + (1-gate)*x0
// MODE 3: LIN  -> X@W^T + bias
template<int MODE>
__global__ __launch_bounds__(256, 2) void gemm_k(
    const float* __restrict__ X, const float* __restrict__ W0,
    const float* __restrict__ W1, const float* __restrict__ bias,
    const float* __restrict__ aux0, const float* __restrict__ aux1,
    float* __restrict__ out0, float* __restrict__ out1) {
  constexpr bool KV = (MODE == 0);
  __shared__ float Xs[32][68];
  __shared__ float Ws[32][68];
  __shared__ float Ws2[KV ? 32 : 1][68];
  const int tid = threadIdx.x;
  const int m0 = blockIdx.x * 64, n0 = blockIdx.y * 64;
  const int tm = tid >> 4, tn = tid & 15;
  const int lr = tid >> 3;            // staging row 0..31
  const int lc = (tid & 7) * 4;       // staging k offset
  float acc[4][4] = {};
  float acc2[KV ? 4 : 1][4] = {};

  for (int k0 = 0; k0 < 512; k0 += 32) {
    const float4 xa = *(const float4*)&X[(size_t)(m0 + lr) * 512 + k0 + lc];
    const float4 xb = *(const float4*)&X[(size_t)(m0 + 32 + lr) * 512 + k0 + lc];
    const float4 wa = *(const float4*)&W0[(size_t)(n0 + lr) * 512 + k0 + lc];
    const float4 wb = *(const float4*)&W0[(size_t)(n0 + 32 + lr) * 512 + k0 + lc];
    float4 va, vb;
    if constexpr (KV) {
      va = *(const float4*)&W1[(size_t)(n0 + lr) * 512 + k0 + lc];
      vb = *(const float4*)&W1[(size_t)(n0 + 32 + lr) * 512 + k0 + lc];
    }
    __syncthreads();
    Xs[lc+0][lr] = xa.x; Xs[lc+1][lr] = xa.y; Xs[lc+2][lr] = xa.z; Xs[lc+3][lr] = xa.w;
    Xs[lc+0][lr+32] = xb.x; Xs[lc+1][lr+32] = xb.y; Xs[lc+2][lr+32] = xb.z; Xs[lc+3][lr+32] = xb.w;
    Ws[lc+0][lr] = wa.x; Ws[lc+1][lr] = wa.y; Ws[lc+2][lr] = wa.z; Ws[lc+3][lr] = wa.w;
    Ws[lc+0][lr+32] = wb.x; Ws[lc+1][lr+32] = wb.y; Ws[lc+2][lr+32] = wb.z; Ws[lc+3][lr+32] = wb.w;
    if constexpr (KV) {
      Ws2[lc+0][lr] = va.x; Ws2[lc+1][lr] = va.y; Ws2[lc+2][lr] = va.z; Ws2[lc+3][lr] = va.w;
      Ws2[lc+0][lr+32] = vb.x; Ws2[lc+1][lr+32] = vb.y; Ws2[lc+2][lr+32] = vb.z; Ws2[lc+3][lr+32] = vb.w;
    }
    __syncthreads();
    #pragma unroll
    for (int kk = 0; kk < 32; ++kk) {
      float4 xv = *(const float4*)&Xs[kk][tm * 4];
      float4 wv = *(const float4*)&Ws[kk][tn * 4];
      const float* xf = (const float*)&xv;
      const float* wf = (const float*)&wv;
      #pragma unroll
      for (int i = 0; i < 4; ++i)
        #pragma unroll
        for (int j = 0; j < 4; ++j)
          acc[i][j] += xf[i] * wf[j];
      if constexpr (KV) {
        float4 wv2 = *(const float4*)&Ws2[kk][tn * 4];
        const float* w2 = (const float*)&wv2;
        #pragma unroll
        for (int i = 0; i < 4; ++i)
          #pragma unroll
          for (int j = 0; j < 4; ++j)
            acc2[i][j] += xf[i] * w2[j];
      }
    }
  }

  if constexpr (MODE == 0) {          // KV epilogue: reduce over t (rows), atomic to k_sum/kv_sum
    __syncthreads();
    float* red = &Xs[0][0];           // 128 floats scratch
    if (tid < 128) red[tid] = 0.f;
    __syncthreads();
    #pragma unroll
    for (int j = 0; j < 4; ++j) {
      float ks = 0.f, kvs = 0.f;
      #pragma unroll
      for (int i = 0; i < 4; ++i) {
        float kk_ = phi_f(acc[i][j]);
        ks += kk_;
        kvs += kk_ * acc2[i][j];
      }
      atomicAdd(&red[(tn * 4 + j) * 2 + 0], ks);
      atomicAdd(&red[(tn * 4 + j) * 2 + 1], kvs);
    }
    __syncthreads();
    if (tid < 64) {
      int b = m0 >> 11;               // row block -> batch (2048 rows per batch)
      atomicAdd(&out0[b * 512 + n0 + tid], red[tid * 2 + 0]);
      atomicAdd(&out1[b * 512 + n0 + tid], red[tid * 2 + 1]);
    }
  } else if constexpr (MODE == 1) {   // Q epilogue: num/den partials
    int b = m0 >> 11;
    float kvv[4], ksv[4];
    #pragma unroll
    for (int j = 0; j < 4; ++j) {
      int n = n0 + tn * 4 + j;
      kvv[j] = aux0[b * 512 + n];
      ksv[j] = aux1[b * 512 + n];
    }
    __syncthreads();
    float* red = &Xs[0][0];
    if (tid < 128) red[tid] = 0.f;
    __syncthreads();
    #pragma unroll
    for (int i = 0; i < 4; ++i) {
      float np = 0.f, dp = 0.f;
      #pragma unroll
      for (int j = 0; j < 4; ++j) {
        float q = phi_f(acc[i][j]);
        np += q * kvv[j];
        dp += q * ksv[j];
      }
      atomicAdd(&red[(tm * 4 + i) * 2 + 0], np);
      atomicAdd(&red[(tm * 4 + i) * 2 + 1], dp);
    }
    __syncthreads();
    if (tid < 64) {
      int m = m0 + tid, h = n0 >> 8;
      atomicAdd(&out0[((size_t)m * 2 + h) * 2 + 0], red[tid * 2 + 0]);
      atomicAdd(&out0[((size_t)m * 2 + h) * 2 + 1], red[tid * 2 + 1]);
    }
  } else if constexpr (MODE == 2) {   // GATE epilogue: x1 = g*r + (1-g)*x0
    int h = n0 >> 8;
    #pragma unroll
    for (int i = 0; i < 4; ++i) {
      int m = m0 + tm * 4 + i;
      float rn = aux0[((size_t)m * 2 + h) * 2 + 0];
      float rd = aux0[((size_t)m * 2 + h) * 2 + 1];
      float r = rn / (rd + 1e-6f);
      float4 x0v = *(const float4*)&aux1[(size_t)m * 512 + n0 + tn * 4];
      const float* xf = (const float*)&x0v;
      float4 o;
      float* of = (float*)&o;
      #pragma unroll
      for (int j = 0; j < 4; ++j) {
        int n = n0 + tn * 4 + j;
        float g = sigm_f(acc[i][j] + bias[n]);
        of[j] = g * r + (1.f - g) * xf[j];
      }
      *(float4*)&out0[(size_t)m * 512 + n0 + tn * 4] = o;
    }
  } else {                            // LIN epilogue
    #pragma unroll
    for (int i = 0; i < 4; ++i) {
      int m = m0 + tm * 4 + i;
      float4 o;
      float* of = (float*)&o;
      #pragma unroll
      for (int j = 0; j < 4; ++j)
        of[j] = acc[i][j] + bias[n0 + tn * 4 + j];
      *(float4*)&out0[(size_t)m * 512 + n0 + tn * 4] = o;
    }
  }
}

// ---------------- persistent GRU scan ----------------
// 256 WGs x 256 threads. WG (g = bid>>5, c = bid&31) owns batches g*4..g*4+3,
// j-columns c*16..c*16+15. Thread (j = tid&15, ks = tid>>4) holds weights
// W_h/W_zh rows jg, fast_W col jg, k-slice [ks*32, ks*32+32) in VGPRs.
// h exchange: write-once history hist[t][32][512] pre-filled with qNaN.
// Producers store h_{t+1} into row t (sc0 sc1, fire-and-forget). Consumers
// poll row t-1 directly: MAC the data and detect readiness via NaN
// propagation into am[0][b] (0*NaN=NaN, so any sentinel poisons the sum).

#define ISSUE8(h0,h1,h2,h3,h4_,h5,h6,h7,ptr) \
  asm volatile( \
    "global_load_dwordx4 %0, %8, off sc0 sc1\n\t" \
    "global_load_dwordx4 %1, %8, off offset:16 sc0 sc1\n\t" \
    "global_load_dwordx4 %2, %8, off offset:32 sc0 sc1\n\t" \
    "global_load_dwordx4 %3, %8, off offset:48 sc0 sc1\n\t" \
    "global_load_dwordx4 %4, %8, off offset:64 sc0 sc1\n\t" \
    "global_load_dwordx4 %5, %8, off offset:80 sc0 sc1\n\t" \
    "global_load_dwordx4 %6, %8, off offset:96 sc0 sc1\n\t" \
    "global_load_dwordx4 %7, %8, off offset:112 sc0 sc1" \
    : "=v"(h0), "=v"(h1), "=v"(h2), "=v"(h3), \
      "=v"(h4_), "=v"(h5), "=v"(h6), "=v"(h7) \
    : "v"(ptr))

#define WAIT_TIE(h0,h1,h2,h3,h4_,h5,h6,h7) \
  asm volatile("s_waitcnt vmcnt(0)" \
    : "+v"(h0), "+v"(h1), "+v"(h2), "+v"(h3), \
      "+v"(h4_), "+v"(h5), "+v"(h6), "+v"(h7))

__global__ __launch_bounds__(256, 1) void scan_k(
    const float* __restrict__ xin, const float* __restrict__ xz,
    const float* __restrict__ Wh, const float* __restrict__ Wzh,
    const float* __restrict__ fastW,
    const float* __restrict__ log_tau, const float* __restrict__ log_dt,
    float* __restrict__ hist) {
  __shared__ float red[2][4][16][12];   // [parity][wave][j][m*4+b]
  const int tid = threadIdx.x;
  const int c = blockIdx.x & 31;        // j-chunk
  const int g = blockIdx.x >> 5;        // batch group
  const int lane = tid & 63, w = tid >> 6;
  const int j = tid & 15, ks = tid >> 4;
  const int jg = c * 16 + j;
  const int kb = ks * 32;

  // ---- weights into VGPRs (one-time) ----
  f32x4 wh[8], wz[8], fw[8];
  #pragma unroll
  for (int i = 0; i < 8; ++i) {
    wh[i] = *(const f32x4*)&Wh[(size_t)jg * 512 + kb + i * 4];
    wz[i] = *(const f32x4*)&Wzh[(size_t)jg * 512 + kb + i * 4];
    f32x4 t;
    t.x = fastW[(size_t)(kb + i * 4 + 0) * 512 + jg];
    t.y = fastW[(size_t)(kb + i * 4 + 1) * 512 + jg];
    t.z = fastW[(size_t)(kb + i * 4 + 2) * 512 + jg];
    t.w = fastW[(size_t)(kb + i * 4 + 3) * 512 + jg];
    fw[i] = t;
  }
  // fast_W slice all-zero? (zero slice contributes zero -> skip MAC, any input)
  bool fwz = true;
  #pragma unroll
  for (int i = 0; i < 8; ++i)
    fwz = fwz & (fw[i].x == 0.f) & (fw[i].y == 0.f) & (fw[i].z == 0.f) & (fw[i].w == 0.f);
  // epilogue constants (wave 0: lane = eb*16 + ej)
  const int eb = lane >> 4, ej = lane & 15;
  const int ejg = c * 16 + ej;
  const int bglob = g * 4 + eb;
  const float dtv = expf(log_dt[ejg]);
  const float tauv = expf(log_tau[ejg]);
  float hold = 0.f;
  asm volatile("s_waitcnt vmcnt(0)" ::: "memory");   // weights resident

  for (int t = 0; t < 2048; ++t) {
    // ---- xin/xz for this step (wave 0 only) ----
    float pxin, pxz;
    if (w == 0) {
      size_t xo = ((size_t)bglob * T_ + t) * 512 + ejg;
      const float* xip = xin + xo;
      const float* xzp = xz + xo;
      asm volatile("global_load_dword %0, %2, off\n\t"
                   "global_load_dword %1, %3, off"
                   : "=v"(pxin), "=v"(pxz) : "v"(xip), "v"(xzp));
    }
    // ---- load h_t slices (write-once history, NaN-validated), MAC ----
    float am[3][4];
    #pragma unroll
    for (int m = 0; m < 3; ++m)
      #pragma unroll
      for (int b = 0; b < 4; ++b) am[m][b] = 0.f;
    if (t != 0) {
      const float* hrow = hist + (size_t)(t - 1) * (B_ * H_);
      f32x4 hv[4][8];
      #pragma unroll
      for (int b = 0; b < 4; ++b) {
        const float* hp = hrow + ((g * 4 + b) * 512 + kb);
        ISSUE8(hv[b][0], hv[b][1], hv[b][2], hv[b][3],
               hv[b][4], hv[b][5], hv[b][6], hv[b][7], hp);
      }
      unsigned done = 0;
      while (true) {
        #pragma unroll
        for (int b = 0; b < 4; ++b) {
          if (!(done & (1u << b))) {
            WAIT_TIE(hv[b][0], hv[b][1], hv[b][2], hv[b][3],
                     hv[b][4], hv[b][5], hv[b][6], hv[b][7]);
            float a0 = 0.f, a1 = 0.f, a2 = 0.f;
            #pragma unroll
            for (int i = 0; i < 8; ++i) {
              f32x4 h4 = hv[b][i];
              a0 += wh[i].x * h4.x + wh[i].y * h4.y + wh[i].z * h4.z + wh[i].w * h4.w;
              a1 += wz[i].x * h4.x + wz[i].y * h4.y + wz[i].z * h4.z + wz[i].w * h4.w;
            }
            if (!fwz) {
              #pragma unroll
              for (int i = 0; i < 8; ++i) {
                f32x4 h4 = hv[b][i];
                a2 += fw[i].x * h4.x + fw[i].y * h4.y + fw[i].z * h4.z + fw[i].w * h4.w;
              }
            }
            // bitwise NaN/Inf exponent check (fast-math-proof): a0 is NaN iff
            // any of the 32 h floats for batch b is still the sentinel.
            if ((__float_as_uint(a0) & 0x7F800000u) != 0x7F800000u) {
              am[0][b] = a0; am[1][b] = a1; am[2][b] = a2;
              done |= 1u << b;
            } else {
              const float* hp = hrow + ((g * 4 + b) * 512 + kb);
              ISSUE8(hv[b][0], hv[b][1], hv[b][2], hv[b][3],
                     hv[b][4], hv[b][5], hv[b][6], hv[b][7], hp);
            }
          }
        }
        if (__ballot(done == 0xFu) == ~0ull) break;
      }
    }
    // ---- reduce over ks within wave (ks bits 0,1 = lane bits 4,5) ----
    #pragma unroll
    for (int m = 0; m < 3; ++m)
      #pragma unroll
      for (int b = 0; b < 4; ++b) {
        am[m][b] += __shfl_xor(am[m][b], 16, 64);
        am[m][b] += __shfl_xor(am[m][b], 32, 64);
      }
    if (lane < 16) {
      #pragma unroll
      for (int m = 0; m < 3; ++m)
        #pragma unroll
        for (int b = 0; b < 4; ++b)
          red[t & 1][w][lane][m * 4 + b] = am[m][b];
    }
    __syncthreads();
    // ---- wave 0: cross-wave reduce + nonlinearity + publish ----
    if (w == 0) {
      float s0 = 0.f, s1 = 0.f, s2 = 0.f;
      #pragma unroll
      for (int ww = 0; ww < 4; ++ww) {
        s0 += red[t & 1][ww][ej][0 + eb];
        s1 += red[t & 1][ww][ej][4 + eb];
        s2 += red[t & 1][ww][ej][8 + eb];
      }
      asm volatile("s_waitcnt vmcnt(0)" : "+v"(pxin), "+v"(pxz));  // t==0 path: xin pending
      float u = pxin + s0;
      float f = tanhf(u);
      float hl = hold + dtv * (f - tauv * hold);
      float zv = sigm_f(pxz + s1);
      float slow = (1.f - zv) * hold + zv * hl;
      float hnv = slow + s2;
      hold = hnv;
      // fire-and-forget publish of h_{t+1} into row t (write-once slot)
      float* dst = hist + (size_t)t * (B_ * H_) + bglob * 512 + ejg;
      asm volatile("global_store_dword %0, %1, off sc0 sc1" :: "v"(dst), "v"(hnv) : "memory");
    }
  }
}

// ---------------- pred_error_norm ----------------
__global__ __launch_bounds__(256) void pred_k(const float* __restrict__ hA,
                                              const float* __restrict__ hB,
                                              float* __restrict__ out) {
  const int tid = threadIdx.x;
  float s = 0.f;
  for (int i = tid; i < H_ * B_; i += 256) {
    float a = __hip_atomic_load((const float*)&hA[i], __ATOMIC_RELAXED, __HIP_MEMORY_SCOPE_AGENT);
    float b = __hip_atomic_load((const float*)&hB[i], __ATOMIC_RELAXED, __HIP_MEMORY_SCOPE_AGENT);
    float d = a - b;
    s += d * d;
  }
  #pragma unroll
  for (int m = 1; m < 64; m <<= 1) s += __shfl_xor(s, m, 64);
  __shared__ float r8[4];
  if ((tid & 63) == 0) r8[tid >> 6] = s;
  __syncthreads();
  if (tid == 0) out[0] = sqrtf((r8[0] + r8[1] + r8[2] + r8[3]) * (1.f / (H_ * B_)));
}

// ---------------- LayerNorm over h_last ([32][512] row-major) ----------------
__global__ __launch_bounds__(256) void ln_k(const float* __restrict__ h0,
                                            const float* __restrict__ g,
                                            const float* __restrict__ be,
                                            float* __restrict__ hln,        // [32][512]
                                            float* __restrict__ outh) {
  const int b = blockIdx.x, tid = threadIdx.x;
  float v0 = __hip_atomic_load((const float*)&h0[b * 512 + tid], __ATOMIC_RELAXED, __HIP_MEMORY_SCOPE_AGENT);
  float v1 = __hip_atomic_load((const float*)&h0[b * 512 + tid + 256], __ATOMIC_RELAXED, __HIP_MEMORY_SCOPE_AGENT);
  float s = v0 + v1;
  #pragma unroll
  for (int m = 1; m < 64; m <<= 1) s += __shfl_xor(s, m, 64);
  __shared__ float r8[8];
  if ((tid & 63) == 0) r8[tid >> 6] = s;
  __syncthreads();
  float mu = (r8[0] + r8[1] + r8[2] + r8[3]) * (1.f / 512.f);
  float d0 = v0 - mu, d1 = v1 - mu;
  float s2 = d0 * d0 + d1 * d1;
  #pragma unroll
  for (int m = 1; m < 64; m <<= 1) s2 += __shfl_xor(s2, m, 64);
  if ((tid & 63) == 0) r8[4 + (tid >> 6)] = s2;
  __syncthreads();
  float var = (r8[4] + r8[5] + r8[6] + r8[7]) * (1.f / 512.f);
  float inv = rsqrtf(var + 1e-5f);
  float y0 = d0 * inv * g[tid] + be[tid];
  float y1 = d1 * inv * g[tid + 256] + be[tid + 256];
  hln[b * 512 + tid] = y0;
  hln[b * 512 + tid + 256] = y1;
  outh[b * 512 + tid] = y0;
  outh[b * 512 + tid + 256] = y1;
}

// ---------------- LM head: logits = hln @ Wlm^T + blm ----------------
__global__ __launch_bounds__(256, 2) void logits_k(const float* __restrict__ hln,
                                                   const float* __restrict__ Wlm,
                                                   const float* __restrict__ blm,
                                                   float* __restrict__ out) {
  __shared__ float hs[32 * 513];
  const int tid = threadIdx.x;
  for (int idx = tid; idx < 16384; idx += 256) {
    int b = idx >> 9, k = idx & 511;
    hs[b * 513 + k] = hln[idx];
  }
  __syncthreads();
  const int lane = tid & 63, w = tid >> 6;
  const int b = lane & 31, kh = lane >> 5;
  const float* hb = &hs[b * 513 + kh * 256];
  const int vbase = blockIdx.x * 64 + w * 16;
  for (int r4 = 0; r4 < 16; r4 += 4) {
    int v = vbase + r4;
    int v0i = (v + 0 < V_) ? v + 0 : V_ - 1;
    int v1i = (v + 1 < V_) ? v + 1 : V_ - 1;
    int v2i = (v + 2 < V_) ? v + 2 : V_ - 1;
    int v3i = (v + 3 < V_) ? v + 3 : V_ - 1;
    const float4* w0 = (const float4*)&Wlm[(size_t)v0i * 512 + kh * 256];
    const float4* w1 = (const float4*)&Wlm[(size_t)v1i * 512 + kh * 256];
    const float4* w2 = (const float4*)&Wlm[(size_t)v2i * 512 + kh * 256];
    const float4* w3 = (const float4*)&Wlm[(size_t)v3i * 512 + kh * 256];
    float a0 = 0.f, a1 = 0.f, a2 = 0.f, a3 = 0.f;
    #pragma unroll 8
    for (int q = 0; q < 64; ++q) {
      float h0 = hb[q * 4 + 0], h1 = hb[q * 4 + 1], h2 = hb[q * 4 + 2], h3 = hb[q * 4 + 3];
      float4 x;
      x = w0[q]; a0 += x.x * h0 + x.y * h1 + x.z * h2 + x.w * h3;
      x = w1[q]; a1 += x.x * h0 + x.y * h1 + x.z * h2 + x.w * h3;
      x = w2[q]; a2 += x.x * h0 + x.y * h1 + x.z * h2 + x.w * h3;
      x = w3[q]; a3 += x.x * h0 + x.y * h1 + x.z * h2 + x.w * h3;
    }
    a0 += __shfl_xor(a0, 32, 64);
    a1 += __shfl_xor(a1, 32, 64);
    a2 += __shfl_xor(a2, 32, 64);
    a3 += __shfl_xor(a3, 32, 64);
    if (lane < 32) {
      if (v + 0 < V_) out[(size_t)b * V_ + v + 0] = a0 + blm[v + 0];
      if (v + 1 < V_) out[(size_t)b * V_ + v + 1] = a1 + blm[v + 1];
      if (v + 2 < V_) out[(size_t)b * V_ + v + 2] = a2 + blm[v + 2];
      if (v + 3 < V_) out[(size_t)b * V_ + v + 3] = a3 + blm[v + 3];
    }
  }
}

extern "C" void kernel_launch(void* const* d_in, const int* in_sizes, int n_in,
                              void* d_out, int out_size, void* d_ws, size_t ws_size,
                              hipStream_t stream) {
  const int*   ids     = (const int*)d_in[0];
  const float* emb     = (const float*)d_in[1];
  const float* Wq      = (const float*)d_in[2];
  const float* Wk      = (const float*)d_in[3];
  const float* Wv      = (const float*)d_in[4];
  // d_in[5] = Wo (unused in forward)
  const float* Wg      = (const float*)d_in[6];
  const float* bg      = (const float*)d_in[7];
  const float* W_in    = (const float*)d_in[8];
  const float* b_in    = (const float*)d_in[9];
  const float* W_h     = (const float*)d_in[10];
  const float* log_tau = (const float*)d_in[11];
  const float* log_dt  = (const float*)d_in[12];
  const float* W_zx    = (const float*)d_in[13];
  const float* b_zx    = (const float*)d_in[14];
  const float* W_zh    = (const float*)d_in[15];
  const float* fast_W  = (const float*)d_in[16];
  const float* ln_g    = (const float*)d_in[17];
  const float* ln_b    = (const float*)d_in[18];
  const float* Wlm     = (const float*)d_in[19];
  const float* blm     = (const float*)d_in[20];

  char* ws = (char*)d_ws;
  float* x0    = (float*)(ws + OFF_X0);
  float* x1    = (float*)(ws + OFF_X1);    // becomes h history after LIN GEMMs
  float* xzb   = (float*)(ws + OFF_XZ);
  float* rbuf  = (float*)(ws + OFF_RBUF);
  float* ksum  = (float*)(ws + OFF_KSUM);
  float* kvsum = (float*)(ws + OFF_KVSUM);
  float* hln   = (float*)(ws + OFF_HLN);
  float* out   = (float*)d_out;

  const int nzero = (int)ZERO_F4;
  zero_k<<<dim3((nzero + 255) / 256), dim3(256), 0, stream>>>((float4*)(ws + OFF_SMALL), nzero);
  embed_k<<<dim3(BT_ * 128 / 256), dim3(256), 0, stream>>>(ids, emb, x0);

  dim3 gg(BT_ / 64, 8);
  gemm_k<0><<<gg, dim3(256), 0, stream>>>(x0, Wk, Wv, nullptr, nullptr, nullptr, ksum, kvsum);
  gemm_k<1><<<gg, dim3(256), 0, stream>>>(x0, Wq, nullptr, nullptr, kvsum, ksum, rbuf, nullptr);
  gemm_k<2><<<gg, dim3(256), 0, stream>>>(x0, Wg, nullptr, bg, rbuf, x0, x1, nullptr);
  gemm_k<3><<<gg, dim3(256), 0, stream>>>(x1, W_in, nullptr, b_in, nullptr, nullptr, x0, nullptr);
  gemm_k<3><<<gg, dim3(256), 0, stream>>>(x1, W_zx, nullptr, b_zx, nullptr, nullptr, xzb, nullptr);

  // x1 is now dead -> reuse as write-once h history, sentinel-filled with qNaN.
  // (2048 rows x 32 x 512 floats = exactly BT_*D_*4 bytes)
  fillnan_k<<<dim3(BT_ * D_ / 4 / 256), dim3(256), 0, stream>>>((uint4*)x1);

  scan_k<<<dim3(256), dim3(256), 0, stream>>>(x0, xzb, W_h, W_zh, fast_W, log_tau, log_dt, x1);

  // h_last = h_2048 (row 2047), h_prev = h_2047 (row 2046)
  float* hlast = x1 + (size_t)2047 * (B_ * H_);
  float* hprev = x1 + (size_t)2046 * (B_ * H_);
  pred_k<<<dim3(1), dim3(256), 0, stream>>>(hlast, hprev, out + (size_t)B_ * V_ + (size_t)B_ * H_);
  ln_k<<<dim3(32), dim3(256), 0, stream>>>(hlast, ln_g, ln_b, hln, out + (size_t)B_ * V_);
  logits_k<<<dim3((V_ + 63) / 64), dim3(256), 0, stream>>>(hln, Wlm, blm, out);
}

// Round 2
// 7691.262 us; speedup vs baseline: 1.8204x; 1.8204x over previous
//
#include <hip/hip_runtime.h>
#include <cstdint>
#include <cstddef>

// MirrorLM forward, fp32 end-to-end.
//  B=32 T=2048 V=50257 D=H=512 NH=2 HD=256
// R5: scan repartitioned batch-local: 256 WGs x 1024 threads, WG (b,q) owns
//  64 columns of ONE batch (sync group = 8 WGs, was 32).
//  - thread (w=tid>>6, lane) = k-slice [w*32,w*32+32) of col q*64+lane,
//    96 weight floats in VGPRs (wh/wz/fw)
//  - h exchange: write-once NaN-sentinel history (kept from R4), but polling
//    is PER-WAVE independent: each wave validates its own 32-float slice via
//    a NaN-propagating sum, re-issues only its own 8 loads (R4's bug was
//    cross-batch vmcnt(0) serialization of retries)
//  - 2 of 16 waves read their own WG's h from LDS (no RT at all)
//  - producers fire-and-forget sc0sc1 stores; x prefetched one step ahead
// GEMM phase unchanged from R2 (passed, absmax 0.0039).

#define B_ 32
#define T_ 2048
#define V_ 50257
#define D_ 512
#define H_ 512
#define NH_ 2
#define BT_ (B_*T_)   // 65536

typedef float f32x4 __attribute__((ext_vector_type(4)));

// ---- workspace layout (bytes). Requires ~404 MB of d_ws. ----
#define OFF_X0    ((size_t)0)                          // [BT][512] f32, later reused as xin
#define OFF_X1    (OFF_X0 + (size_t)BT_*D_*4)          // [BT][512] f32 (gated x), reused as h history
#define OFF_XZ    (OFF_X1 + (size_t)BT_*D_*4)          // [BT][512] f32 (xz)
#define OFF_SMALL (OFF_XZ + (size_t)BT_*D_*4)
#define OFF_RBUF  (OFF_SMALL)                          // [BT][NH][2] f32 num/den = 1 MB
#define OFF_KSUM  (OFF_RBUF + (size_t)BT_*NH_*2*4)     // [B][512]
#define OFF_KVSUM (OFF_KSUM + (size_t)B_*D_*4)         // [B][512]
#define OFF_FLAGS (OFF_KVSUM + (size_t)B_*D_*4)        // (unused in R5, kept in zero span)
#define OFF_HBUF  (OFF_FLAGS + 16384)                  // (unused in R5)
#define OFF_HLN   (OFF_HBUF + (size_t)2*B_*H_*4)       // LN'd h: [32][512]
#define ZERO_F4   ((OFF_HBUF - OFF_SMALL) / 16)        // zero RBUF..FLAGS

__device__ __forceinline__ float phi_f(float x) {           // elu(x)+1
  return x > 0.f ? x + 1.f : expf(x);
}
__device__ __forceinline__ float sigm_f(float x) {
  return 1.f / (1.f + expf(-x));
}

// ---------------- zero small state ----------------
__global__ __launch_bounds__(256) void zero_k(float4* __restrict__ p, int n) {
  int i = blockIdx.x * 256 + threadIdx.x;
  if (i < n) p[i] = make_float4(0.f, 0.f, 0.f, 0.f);
}

// ---------------- NaN-fill the h history (sentinel) ----------------
__global__ __launch_bounds__(256) void fillnan_k(uint4* __restrict__ p) {
  size_t i = (size_t)blockIdx.x * 256 + threadIdx.x;
  uint4 v;
  v.x = 0x7FC00000u; v.y = 0x7FC00000u; v.z = 0x7FC00000u; v.w = 0x7FC00000u;
  p[i] = v;
}

// ---------------- embedding gather ----------------
__global__ __launch_bounds__(256) void embed_k(const int* __restrict__ ids,
                                               const float* __restrict__ emb,
                                               float* __restrict__ x0) {
  size_t idx = (size_t)blockIdx.x * 256 + threadIdx.x;   // over BT*128 float4
  int row = (int)(idx >> 7), c = (int)(idx & 127);
  int id = ids[row];
  ((float4*)x0)[idx] = ((const float4*)emb)[(size_t)id * 128 + c];
}

// ---------------- tiled fp32 GEMM, Y = X @ W^T, 64x64x32 tiles ----------------
// MODE 0: KV   -> phi(X@Wk^T), X@Wv^T; atomicAdd k_sum/kv_sum (reduce over t)
// MODE 1: Q    -> phi(X@Wq^T); atomicAdd num/den partials vs kv_sum/k_sum
// MODE 2: GATE -> gate=sigmoid(X@Wg^T+bg); x1 = gate*r + (1-gate)*x0
// MODE 3: LIN  -> X@W^T + bias
template<int MODE>
__global__ __launch_bounds__(256, 2) void gemm_k(
    const float* __restrict__ X, const float* __restrict__ W0,
    const float* __restrict__ W1, const float* __restrict__ bias,
    const float* __restrict__ aux0, const float* __restrict__ aux1,
    float* __restrict__ out0, float* __restrict__ out1) {
  constexpr bool KV = (MODE == 0);
  __shared__ float Xs[32][68];
  __shared__ float Ws[32][68];
  __shared__ float Ws2[KV ? 32 : 1][68];
  const int tid = threadIdx.x;
  const int m0 = blockIdx.x * 64, n0 = blockIdx.y * 64;
  const int tm = tid >> 4, tn = tid & 15;
  const int lr = tid >> 3;            // staging row 0..31
  const int lc = (tid & 7) * 4;       // staging k offset
  float acc[4][4] = {};
  float acc2[KV ? 4 : 1][4] = {};

  for (int k0 = 0; k0 < 512; k0 += 32) {
    const float4 xa = *(const float4*)&X[(size_t)(m0 + lr) * 512 + k0 + lc];
    const float4 xb = *(const float4*)&X[(size_t)(m0 + 32 + lr) * 512 + k0 + lc];
    const float4 wa = *(const float4*)&W0[(size_t)(n0 + lr) * 512 + k0 + lc];
    const float4 wb = *(const float4*)&W0[(size_t)(n0 + 32 + lr) * 512 + k0 + lc];
    float4 va, vb;
    if constexpr (KV) {
      va = *(const float4*)&W1[(size_t)(n0 + lr) * 512 + k0 + lc];
      vb = *(const float4*)&W1[(size_t)(n0 + 32 + lr) * 512 + k0 + lc];
    }
    __syncthreads();
    Xs[lc+0][lr] = xa.x; Xs[lc+1][lr] = xa.y; Xs[lc+2][lr] = xa.z; Xs[lc+3][lr] = xa.w;
    Xs[lc+0][lr+32] = xb.x; Xs[lc+1][lr+32] = xb.y; Xs[lc+2][lr+32] = xb.z; Xs[lc+3][lr+32] = xb.w;
    Ws[lc+0][lr] = wa.x; Ws[lc+1][lr] = wa.y; Ws[lc+2][lr] = wa.z; Ws[lc+3][lr] = wa.w;
    Ws[lc+0][lr+32] = wb.x; Ws[lc+1][lr+32] = wb.y; Ws[lc+2][lr+32] = wb.z; Ws[lc+3][lr+32] = wb.w;
    if constexpr (KV) {
      Ws2[lc+0][lr] = va.x; Ws2[lc+1][lr] = va.y; Ws2[lc+2][lr] = va.z; Ws2[lc+3][lr] = va.w;
      Ws2[lc+0][lr+32] = vb.x; Ws2[lc+1][lr+32] = vb.y; Ws2[lc+2][lr+32] = vb.z; Ws2[lc+3][lr+32] = vb.w;
    }
    __syncthreads();
    #pragma unroll
    for (int kk = 0; kk < 32; ++kk) {
      float4 xv = *(const float4*)&Xs[kk][tm * 4];
      float4 wv = *(const float4*)&Ws[kk][tn * 4];
      const float* xf = (const float*)&xv;
      const float* wf = (const float*)&wv;
      #pragma unroll
      for (int i = 0; i < 4; ++i)
        #pragma unroll
        for (int j = 0; j < 4; ++j)
          acc[i][j] += xf[i] * wf[j];
      if constexpr (KV) {
        float4 wv2 = *(const float4*)&Ws2[kk][tn * 4];
        const float* w2 = (const float*)&wv2;
        #pragma unroll
        for (int i = 0; i < 4; ++i)
          #pragma unroll
          for (int j = 0; j < 4; ++j)
            acc2[i][j] += xf[i] * w2[j];
      }
    }
  }

  if constexpr (MODE == 0) {          // KV epilogue: reduce over t (rows), atomic to k_sum/kv_sum
    __syncthreads();
    float* red = &Xs[0][0];           // 128 floats scratch
    if (tid < 128) red[tid] = 0.f;
    __syncthreads();
    #pragma unroll
    for (int j = 0; j < 4; ++j) {
      float ks = 0.f, kvs = 0.f;
      #pragma unroll
      for (int i = 0; i < 4; ++i) {
        float kk_ = phi_f(acc[i][j]);
        ks += kk_;
        kvs += kk_ * acc2[i][j];
      }
      atomicAdd(&red[(tn * 4 + j) * 2 + 0], ks);
      atomicAdd(&red[(tn * 4 + j) * 2 + 1], kvs);
    }
    __syncthreads();
    if (tid < 64) {
      int b = m0 >> 11;               // row block -> batch (2048 rows per batch)
      atomicAdd(&out0[b * 512 + n0 + tid], red[tid * 2 + 0]);
      atomicAdd(&out1[b * 512 + n0 + tid], red[tid * 2 + 1]);
    }
  } else if constexpr (MODE == 1) {   // Q epilogue: num/den partials
    int b = m0 >> 11;
    float kvv[4], ksv[4];
    #pragma unroll
    for (int j = 0; j < 4; ++j) {
      int n = n0 + tn * 4 + j;
      kvv[j] = aux0[b * 512 + n];
      ksv[j] = aux1[b * 512 + n];
    }
    __syncthreads();
    float* red = &Xs[0][0];
    if (tid < 128) red[tid] = 0.f;
    __syncthreads();
    #pragma unroll
    for (int i = 0; i < 4; ++i) {
      float np = 0.f, dp = 0.f;
      #pragma unroll
      for (int j = 0; j < 4; ++j) {
        float q = phi_f(acc[i][j]);
        np += q * kvv[j];
        dp += q * ksv[j];
      }
      atomicAdd(&red[(tm * 4 + i) * 2 + 0], np);
      atomicAdd(&red[(tm * 4 + i) * 2 + 1], dp);
    }
    __syncthreads();
    if (tid < 64) {
      int m = m0 + tid, h = n0 >> 8;
      atomicAdd(&out0[((size_t)m * 2 + h) * 2 + 0], red[tid * 2 + 0]);
      atomicAdd(&out0[((size_t)m * 2 + h) * 2 + 1], red[tid * 2 + 1]);
    }
  } else if constexpr (MODE == 2) {   // GATE epilogue: x1 = g*r + (1-g)*x0
    int h = n0 >> 8;
    #pragma unroll
    for (int i = 0; i < 4; ++i) {
      int m = m0 + tm * 4 + i;
      float rn = aux0[((size_t)m * 2 + h) * 2 + 0];
      float rd = aux0[((size_t)m * 2 + h) * 2 + 1];
      float r = rn / (rd + 1e-6f);
      float4 x0v = *(const float4*)&aux1[(size_t)m * 512 + n0 + tn * 4];
      const float* xf = (const float*)&x0v;
      float4 o;
      float* of = (float*)&o;
      #pragma unroll
      for (int j = 0; j < 4; ++j) {
        int n = n0 + tn * 4 + j;
        float g = sigm_f(acc[i][j] + bias[n]);
        of[j] = g * r + (1.f - g) * xf[j];
      }
      *(float4*)&out0[(size_t)m * 512 + n0 + tn * 4] = o;
    }
  } else {                            // LIN epilogue
    #pragma unroll
    for (int i = 0; i < 4; ++i) {
      int m = m0 + tm * 4 + i;
      float4 o;
      float* of = (float*)&o;
      #pragma unroll
      for (int j = 0; j < 4; ++j)
        of[j] = acc[i][j] + bias[n0 + tn * 4 + j];
      *(float4*)&out0[(size_t)m * 512 + n0 + tn * 4] = o;
    }
  }
}

// ---------------- persistent GRU scan (batch-local, 8-WG groups) ----------------
// Grid: 256 WGs x 1024 threads. WG (b = bid>>3, q = bid&7) owns columns
// q*64..q*64+63 of batch b. Thread (w = tid>>6 = k-slice, lane = tid&63 = col):
// holds W_h/W_zh rows (q*64+lane), fast_W col, k-slice [w*32,w*32+32) in VGPRs.
// h exchange: write-once history hist[t][32][512], NaN-prefilled. Wave w's
// k-slice belongs to column octant (w>>1): if that's this WG (src==q), h comes
// from LDS (same-WG, no RT). Otherwise poll hist row t-1 per-wave: load 32
// floats, validate via NaN-propagating sum, re-issue only own 8 loads.

#define ISSUE8(h0,h1,h2,h3,h4_,h5,h6,h7,ptr) \
  asm volatile( \
    "global_load_dwordx4 %0, %8, off sc0 sc1\n\t" \
    "global_load_dwordx4 %1, %8, off offset:16 sc0 sc1\n\t" \
    "global_load_dwordx4 %2, %8, off offset:32 sc0 sc1\n\t" \
    "global_load_dwordx4 %3, %8, off offset:48 sc0 sc1\n\t" \
    "global_load_dwordx4 %4, %8, off offset:64 sc0 sc1\n\t" \
    "global_load_dwordx4 %5, %8, off offset:80 sc0 sc1\n\t" \
    "global_load_dwordx4 %6, %8, off offset:96 sc0 sc1\n\t" \
    "global_load_dwordx4 %7, %8, off offset:112 sc0 sc1" \
    : "=v"(h0), "=v"(h1), "=v"(h2), "=v"(h3), \
      "=v"(h4_), "=v"(h5), "=v"(h6), "=v"(h7) \
    : "v"(ptr))

#define WAIT_TIE(h0,h1,h2,h3,h4_,h5,h6,h7) \
  asm volatile("s_waitcnt vmcnt(0)" \
    : "+v"(h0), "+v"(h1), "+v"(h2), "+v"(h3), \
      "+v"(h4_), "+v"(h5), "+v"(h6), "+v"(h7))

__global__ __launch_bounds__(1024) void scan_k(
    const float* __restrict__ xin, const float* __restrict__ xz,
    const float* __restrict__ Wh, const float* __restrict__ Wzh,
    const float* __restrict__ fastW,
    const float* __restrict__ log_tau, const float* __restrict__ log_dt,
    float* __restrict__ hist) {
  __shared__ float red[16][64][3];              // [k-slice][col][mat] partials
  __shared__ __align__(16) float h_lds[2][64];  // own octant's h, double-buffered
  const int tid = threadIdx.x;
  const int b = blockIdx.x >> 3;        // batch 0..31
  const int q = blockIdx.x & 7;         // column octant 0..7
  const int w = tid >> 6;               // wave = k-slice 0..15
  const int lane = tid & 63;            // col within octant
  const int jg = q * 64 + lane;         // global column
  const int kb = w * 32;                // k base of this wave's slice
  const int src = w >> 1;               // octant that produces h[kb..kb+32)

  // ---- weights into VGPRs (one-time): 96 floats/thread ----
  f32x4 wh[8], wz[8], fw[8];
  #pragma unroll
  for (int i = 0; i < 8; ++i) {
    wh[i] = *(const f32x4*)&Wh[(size_t)jg * 512 + kb + i * 4];
    wz[i] = *(const f32x4*)&Wzh[(size_t)jg * 512 + kb + i * 4];
    f32x4 tv;
    tv.x = fastW[(size_t)(kb + i * 4 + 0) * 512 + jg];
    tv.y = fastW[(size_t)(kb + i * 4 + 1) * 512 + jg];
    tv.z = fastW[(size_t)(kb + i * 4 + 2) * 512 + jg];
    tv.w = fastW[(size_t)(kb + i * 4 + 3) * 512 + jg];
    fw[i] = tv;
  }
  // fast_W slice all-zero? (zero slice contributes zero -> skip MAC, any input)
  bool fwz = true;
  #pragma unroll
  for (int i = 0; i < 8; ++i)
    fwz = fwz & (fw[i].x == 0.f) & (fw[i].y == 0.f) & (fw[i].z == 0.f) & (fw[i].w == 0.f);

  const float dtv = expf(log_dt[jg]);
  const float tauv = expf(log_tau[jg]);
  float hold = 0.f;
  float pxin = 0.f, pxz = 0.f;
  if (w == 0) {                         // prefetch x for t=0
    const float* xip = xin + (size_t)b * T_ * 512 + jg;
    const float* xzp = xz + (size_t)b * T_ * 512 + jg;
    asm volatile("global_load_dword %0, %2, off\n\t"
                 "global_load_dword %1, %3, off"
                 : "=v"(pxin), "=v"(pxz) : "v"(xip), "v"(xzp));
  }

  for (int t = 0; t < T_; ++t) {
    float am0 = 0.f, am1 = 0.f, am2 = 0.f;
    if (t != 0) {
      f32x4 hv[8];
      if (src == q) {
        // own WG produced this slice last step -> LDS, no RT
        const float* hl = &h_lds[t & 1][kb & 63];
        #pragma unroll
        for (int i = 0; i < 8; ++i) hv[i] = *(const f32x4*)(hl + i * 4);
      } else {
        // poll remote slice of hist row t-1 (per-wave independent retry)
        const float* hp = hist + (size_t)(t - 1) * (B_ * H_) + b * 512 + kb;
        ISSUE8(hv[0], hv[1], hv[2], hv[3], hv[4], hv[5], hv[6], hv[7], hp);
        while (true) {
          WAIT_TIE(hv[0], hv[1], hv[2], hv[3], hv[4], hv[5], hv[6], hv[7]);
          f32x4 sv = hv[0] + hv[1] + hv[2] + hv[3] + hv[4] + hv[5] + hv[6] + hv[7];
          float sred = sv.x + sv.y + sv.z + sv.w;      // NaN iff any sentinel left
          if ((__float_as_uint(sred) & 0x7F800000u) != 0x7F800000u) break;
          ISSUE8(hv[0], hv[1], hv[2], hv[3], hv[4], hv[5], hv[6], hv[7], hp);
        }
      }
      #pragma unroll
      for (int i = 0; i < 8; ++i) {
        f32x4 h4 = hv[i];
        am0 += wh[i].x * h4.x + wh[i].y * h4.y + wh[i].z * h4.z + wh[i].w * h4.w;
        am1 += wz[i].x * h4.x + wz[i].y * h4.y + wz[i].z * h4.z + wz[i].w * h4.w;
      }
      if (!fwz) {
        #pragma unroll
        for (int i = 0; i < 8; ++i) {
          f32x4 h4 = hv[i];
          am2 += fw[i].x * h4.x + fw[i].y * h4.y + fw[i].z * h4.z + fw[i].w * h4.w;
        }
      }
    }
    red[w][lane][0] = am0;
    red[w][lane][1] = am1;
    red[w][lane][2] = am2;
    __syncthreads();
    // ---- wave 0: 16-way reduce + nonlinearity + publish ----
    if (w == 0) {
      float s0 = 0.f, s1 = 0.f, s2 = 0.f;
      #pragma unroll
      for (int ww = 0; ww < 16; ++ww) {
        s0 += red[ww][lane][0];
        s1 += red[ww][lane][1];
        s2 += red[ww][lane][2];
      }
      asm volatile("s_waitcnt vmcnt(0)" : "+v"(pxin), "+v"(pxz));  // x prefetched 1 step ago
      float u = pxin + s0;
      float f = tanhf(u);
      float hl2 = hold + dtv * (f - tauv * hold);
      float zv = sigm_f(pxz + s1);
      float slow = (1.f - zv) * hold + zv * hl2;
      float hnv = slow + s2;
      hold = hnv;
      h_lds[(t + 1) & 1][lane] = hnv;   // self-half for next step
      // fire-and-forget publish of h_{t+1} into row t (write-once slot)
      float* dst = hist + (size_t)t * (B_ * H_) + b * 512 + jg;
      asm volatile("global_store_dword %0, %1, off sc0 sc1" :: "v"(dst), "v"(hnv) : "memory");
      if (t + 1 < T_) {                 // prefetch x for t+1
        const float* xip = xin + ((size_t)b * T_ + (t + 1)) * 512 + jg;
        const float* xzp = xz + ((size_t)b * T_ + (t + 1)) * 512 + jg;
        asm volatile("global_load_dword %0, %2, off\n\t"
                     "global_load_dword %1, %3, off"
                     : "=v"(pxin), "=v"(pxz) : "v"(xip), "v"(xzp));
      }
    }
    __syncthreads();
  }
}

// ---------------- pred_error_norm ----------------
__global__ __launch_bounds__(256) void pred_k(const float* __restrict__ hA,
                                              const float* __restrict__ hB,
                                              float* __restrict__ out) {
  const int tid = threadIdx.x;
  float s = 0.f;
  for (int i = tid; i < H_ * B_; i += 256) {
    float a = __hip_atomic_load((const float*)&hA[i], __ATOMIC_RELAXED, __HIP_MEMORY_SCOPE_AGENT);
    float b = __hip_atomic_load((const float*)&hB[i], __ATOMIC_RELAXED, __HIP_MEMORY_SCOPE_AGENT);
    float d = a - b;
    s += d * d;
  }
  #pragma unroll
  for (int m = 1; m < 64; m <<= 1) s += __shfl_xor(s, m, 64);
  __shared__ float r8[4];
  if ((tid & 63) == 0) r8[tid >> 6] = s;
  __syncthreads();
  if (tid == 0) out[0] = sqrtf((r8[0] + r8[1] + r8[2] + r8[3]) * (1.f / (H_ * B_)));
}

// ---------------- LayerNorm over h_last ([32][512] row-major) ----------------
__global__ __launch_bounds__(256) void ln_k(const float* __restrict__ h0,
                                            const float* __restrict__ g,
                                            const float* __restrict__ be,
                                            float* __restrict__ hln,        // [32][512]
                                            float* __restrict__ outh) {
  const int b = blockIdx.x, tid = threadIdx.x;
  float v0 = __hip_atomic_load((const float*)&h0[b * 512 + tid], __ATOMIC_RELAXED, __HIP_MEMORY_SCOPE_AGENT);
  float v1 = __hip_atomic_load((const float*)&h0[b * 512 + tid + 256], __ATOMIC_RELAXED, __HIP_MEMORY_SCOPE_AGENT);
  float s = v0 + v1;
  #pragma unroll
  for (int m = 1; m < 64; m <<= 1) s += __shfl_xor(s, m, 64);
  __shared__ float r8[8];
  if ((tid & 63) == 0) r8[tid >> 6] = s;
  __syncthreads();
  float mu = (r8[0] + r8[1] + r8[2] + r8[3]) * (1.f / 512.f);
  float d0 = v0 - mu, d1 = v1 - mu;
  float s2 = d0 * d0 + d1 * d1;
  #pragma unroll
  for (int m = 1; m < 64; m <<= 1) s2 += __shfl_xor(s2, m, 64);
  if ((tid & 63) == 0) r8[4 + (tid >> 6)] = s2;
  __syncthreads();
  float var = (r8[4] + r8[5] + r8[6] + r8[7]) * (1.f / 512.f);
  float inv = rsqrtf(var + 1e-5f);
  float y0 = d0 * inv * g[tid] + be[tid];
  float y1 = d1 * inv * g[tid + 256] + be[tid + 256];
  hln[b * 512 + tid] = y0;
  hln[b * 512 + tid + 256] = y1;
  outh[b * 512 + tid] = y0;
  outh[b * 512 + tid + 256] = y1;
}

// ---------------- LM head: logits = hln @ Wlm^T + blm ----------------
__global__ __launch_bounds__(256, 2) void logits_k(const float* __restrict__ hln,
                                                   const float* __restrict__ Wlm,
                                                   const float* __restrict__ blm,
                                                   float* __restrict__ out) {
  __shared__ float hs[32 * 513];
  const int tid = threadIdx.x;
  for (int idx = tid; idx < 16384; idx += 256) {
    int b = idx >> 9, k = idx & 511;
    hs[b * 513 + k] = hln[idx];
  }
  __syncthreads();
  const int lane = tid & 63, w = tid >> 6;
  const int b = lane & 31, kh = lane >> 5;
  const float* hb = &hs[b * 513 + kh * 256];
  const int vbase = blockIdx.x * 64 + w * 16;
  for (int r4 = 0; r4 < 16; r4 += 4) {
    int v = vbase + r4;
    int v0i = (v + 0 < V_) ? v + 0 : V_ - 1;
    int v1i = (v + 1 < V_) ? v + 1 : V_ - 1;
    int v2i = (v + 2 < V_) ? v + 2 : V_ - 1;
    int v3i = (v + 3 < V_) ? v + 3 : V_ - 1;
    const float4* w0 = (const float4*)&Wlm[(size_t)v0i * 512 + kh * 256];
    const float4* w1 = (const float4*)&Wlm[(size_t)v1i * 512 + kh * 256];
    const float4* w2 = (const float4*)&Wlm[(size_t)v2i * 512 + kh * 256];
    const float4* w3 = (const float4*)&Wlm[(size_t)v3i * 512 + kh * 256];
    float a0 = 0.f, a1 = 0.f, a2 = 0.f, a3 = 0.f;
    #pragma unroll 8
    for (int q = 0; q < 64; ++q) {
      float h0 = hb[q * 4 + 0], h1 = hb[q * 4 + 1], h2 = hb[q * 4 + 2], h3 = hb[q * 4 + 3];
      float4 x;
      x = w0[q]; a0 += x.x * h0 + x.y * h1 + x.z * h2 + x.w * h3;
      x = w1[q]; a1 += x.x * h0 + x.y * h1 + x.z * h2 + x.w * h3;
      x = w2[q]; a2 += x.x * h0 + x.y * h1 + x.z * h2 + x.w * h3;
      x = w3[q]; a3 += x.x * h0 + x.y * h1 + x.z * h2 + x.w * h3;
    }
    a0 += __shfl_xor(a0, 32, 64);
    a1 += __shfl_xor(a1, 32, 64);
    a2 += __shfl_xor(a2, 32, 64);
    a3 += __shfl_xor(a3, 32, 64);
    if (lane < 32) {
      if (v + 0 < V_) out[(size_t)b * V_ + v + 0] = a0 + blm[v + 0];
      if (v + 1 < V_) out[(size_t)b * V_ + v + 1] = a1 + blm[v + 1];
      if (v + 2 < V_) out[(size_t)b * V_ + v + 2] = a2 + blm[v + 2];
      if (v + 3 < V_) out[(size_t)b * V_ + v + 3] = a3 + blm[v + 3];
    }
  }
}

extern "C" void kernel_launch(void* const* d_in, const int* in_sizes, int n_in,
                              void* d_out, int out_size, void* d_ws, size_t ws_size,
                              hipStream_t stream) {
  const int*   ids     = (const int*)d_in[0];
  const float* emb     = (const float*)d_in[1];
  const float* Wq      = (const float*)d_in[2];
  const float* Wk      = (const float*)d_in[3];
  const float* Wv      = (const float*)d_in[4];
  // d_in[5] = Wo (unused in forward)
  const float* Wg      = (const float*)d_in[6];
  const float* bg      = (const float*)d_in[7];
  const float* W_in    = (const float*)d_in[8];
  const float* b_in    = (const float*)d_in[9];
  const float* W_h     = (const float*)d_in[10];
  const float* log_tau = (const float*)d_in[11];
  const float* log_dt  = (const float*)d_in[12];
  const float* W_zx    = (const float*)d_in[13];
  const float* b_zx    = (const float*)d_in[14];
  const float* W_zh    = (const float*)d_in[15];
  const float* fast_W  = (const float*)d_in[16];
  const float* ln_g    = (const float*)d_in[17];
  const float* ln_b    = (const float*)d_in[18];
  const float* Wlm     = (const float*)d_in[19];
  const float* blm     = (const float*)d_in[20];

  char* ws = (char*)d_ws;
  float* x0    = (float*)(ws + OFF_X0);
  float* x1    = (float*)(ws + OFF_X1);    // becomes h history after LIN GEMMs
  float* xzb   = (float*)(ws + OFF_XZ);
  float* rbuf  = (float*)(ws + OFF_RBUF);
  float* ksum  = (float*)(ws + OFF_KSUM);
  float* kvsum = (float*)(ws + OFF_KVSUM);
  float* hln   = (float*)(ws + OFF_HLN);
  float* out   = (float*)d_out;

  const int nzero = (int)ZERO_F4;
  zero_k<<<dim3((nzero + 255) / 256), dim3(256), 0, stream>>>((float4*)(ws + OFF_SMALL), nzero);
  embed_k<<<dim3(BT_ * 128 / 256), dim3(256), 0, stream>>>(ids, emb, x0);

  dim3 gg(BT_ / 64, 8);
  gemm_k<0><<<gg, dim3(256), 0, stream>>>(x0, Wk, Wv, nullptr, nullptr, nullptr, ksum, kvsum);
  gemm_k<1><<<gg, dim3(256), 0, stream>>>(x0, Wq, nullptr, nullptr, kvsum, ksum, rbuf, nullptr);
  gemm_k<2><<<gg, dim3(256), 0, stream>>>(x0, Wg, nullptr, bg, rbuf, x0, x1, nullptr);
  gemm_k<3><<<gg, dim3(256), 0, stream>>>(x1, W_in, nullptr, b_in, nullptr, nullptr, x0, nullptr);
  gemm_k<3><<<gg, dim3(256), 0, stream>>>(x1, W_zx, nullptr, b_zx, nullptr, nullptr, xzb, nullptr);

  // x1 is now dead -> reuse as write-once h history, sentinel-filled with qNaN.
  // (2048 rows x 32 x 512 floats = exactly BT_*D_*4 bytes)
  fillnan_k<<<dim3(BT_ * D_ / 4 / 256), dim3(256), 0, stream>>>((uint4*)x1);

  scan_k<<<dim3(256), dim3(1024), 0, stream>>>(x0, xzb, W_h, W_zh, fast_W, log_tau, log_dt, x1);

  // h_last = h_2048 (row 2047), h_prev = h_2047 (row 2046)
  float* hlast = x1 + (size_t)2047 * (B_ * H_);
  float* hprev = x1 + (size_t)2046 * (B_ * H_);
  pred_k<<<dim3(1), dim3(256), 0, stream>>>(hlast, hprev, out + (size_t)B_ * V_ + (size_t)B_ * H_);
  ln_k<<<dim3(32), dim3(256), 0, stream>>>(hlast, ln_g, ln_b, hln, out + (size_t)B_ * V_);
  logits_k<<<dim3((V_ + 63) / 64), dim3(256), 0, stream>>>(hln, Wlm, blm, out);
}